// Round 4
// baseline (1192.370 us; speedup 1.0000x reference)
//
#include <hip/hip_runtime.h>
#include <math.h>

typedef __attribute__((ext_vector_type(8))) short bf16x8;
typedef __attribute__((ext_vector_type(4))) float f32x4;
typedef unsigned short u16;

__device__ __forceinline__ u16 f2bf(float f) {
    unsigned u = __builtin_bit_cast(unsigned, f);
    u += 0x7FFFu + ((u >> 16) & 1u);   // RNE
    return (u16)(u >> 16);
}
__device__ __forceinline__ float bf2f(u16 h) {
    unsigned u = ((unsigned)h) << 16;
    return __builtin_bit_cast(float, u);
}

// 8 KB zero page (.bss, zero at module load, never written). OOB lanes of
// global_load_lds point here; sized so a running ic-offset (<= 1024 elems
// + 32 slack) stays inside.
__device__ __align__(64) u16 g_zerow[4096];

// async global->LDS, 16 B per lane; LDS dest = wave-uniform base + lane*16.
// Global source address is PER-LANE (m173) — that's what makes im2col work.
__device__ __forceinline__ void gll16(const u16* g, u16* l) {
    __builtin_amdgcn_global_load_lds(
        (const __attribute__((address_space(1))) unsigned*)g,
        (__attribute__((address_space(3))) unsigned*)l, 16, 0, 0);
}

// =====================================================================
// MFMA GEMM — m97 structure: ALL staging via global_load_lds.
// Lane map per 1024-B gll block: kseg = lane>>4, row = lane&15
//   -> LDS block layout [kseg(4)][row(16)][8 elems] (conflict-free reads)
// Fragment read: block g = (row_global>>4); &S[g*512 + quad*128 + lm*8]
// MODE 0: A = bf16 [M][K] rows (fc, dec)
// MODE 1: A = im2col of bf16 NHWC input, conv3x3 s2 p1; k = tap*CIN+ic
//         per-lane pixel state; tap advance is block-uniform (CIN >= 32)
// OUT  0: bf16 NHWC conv (+bias; optional fused BN stats)
// OUT  1: fp32 atomic NHWC conv (+bias at z==0)
// OUT  4: fp32 atomic plain (no bias)
// OUT  5: bf16 dec-permuted [m][hw][c] (+bias)
// SWIZ 1: 1D grid, nt = id&7 (requires N/BN == 8) -> per-XCD weight L2 reuse
// =====================================================================
template<int MODE, int OUT, int BM, int BN, int SWIZ, bool STATS>
__global__ __launch_bounds__(256, 3)
void gemm(const u16* __restrict__ Abf, const u16* __restrict__ Bw,
          const float* __restrict__ bias, void* __restrict__ outv,
          float* __restrict__ stat,
          int M, int N, int K, int lgC,
          int IH, int IW, int OH, int OW, int zchunk)
{
    constexpr int ACALLS = BM / 64, BCALLS = BN / 64;
    constexpr int RM = BM / 32, RN = BN / 32;
    __shared__ __align__(16) u16 As[BM * 32];
    __shared__ __align__(16) u16 Bs[BN * 32];
    const int t = threadIdx.x;
    const int lane = t & 63, wave = t >> 6;
    const int lm = lane & 15, quad = lane >> 4;
    const int wm = wave & 1, wn = wave >> 1;
    int mt, nt, z;
    if (SWIZ == 1) {
        int mtN = (M + BM - 1) / BM;
        int id = blockIdx.x;
        nt = id & 7; int j = id >> 3;
        mt = j % mtN; z = j / mtN;
    } else { mt = blockIdx.x; nt = blockIdx.y; z = blockIdx.z; }
    const int k0 = z * zchunk, kend = k0 + zchunk;

    // staging lane mapping (conflict-free): kseg-major within each 16-row block
    const int sr16  = lane & 15;          // row within 16-row group
    const int skoff = (lane >> 4) * 8;    // k-elem offset within 32-window

    // ---- B staging pointers (per-lane); OOB rows: zero page, step 0 ----
    const u16* bptr[BCALLS]; int bstep[BCALLS];
    #pragma unroll
    for (int s = 0; s < BCALLS; s++) {
        int rg = nt * BN + s * 64 + (wave << 4) + sr16;
        bool ok = rg < N;
        bptr[s] = ok ? (Bw + (size_t)rg * K + k0 + skoff) : (g_zerow + skoff);
        bstep[s] = ok ? 32 : 0;
    }

    // ---- A staging state ----
    const u16* aptr[ACALLS]; int astep[ACALLS];              // MODE 0
    int p_b[ACALLS], p_oy[ACALLS], p_ox[ACALLS]; bool p_in[ACALLS]; // MODE 1
    const int CIN = 1 << lgC;
    int ic_s = 0, tap_s = 0;
    if constexpr (MODE == 0) {
        #pragma unroll
        for (int s = 0; s < ACALLS; s++) {
            int rg = mt * BM + s * 64 + (wave << 4) + sr16;
            bool ok = rg < M;
            aptr[s] = ok ? (Abf + (size_t)rg * K + k0 + skoff) : (g_zerow + skoff);
            astep[s] = ok ? 32 : 0;
        }
    } else {
        int ohw = OH * OW;
        tap_s = k0 >> lgC; ic_s = k0 & (CIN - 1);
        int ky = tap_s / 3, kx = tap_s - (tap_s / 3) * 3;
        #pragma unroll
        for (int s = 0; s < ACALLS; s++) {
            int rg = mt * BM + s * 64 + (wave << 4) + sr16;
            bool in = rg < M;
            int g = in ? rg : 0;
            int bb = g / ohw; int r = g - bb * ohw;
            int oy = r / OW, ox = r - (r / OW) * OW;
            p_in[s] = in; p_b[s] = bb; p_oy[s] = oy; p_ox[s] = ox;
            int iy = oy * 2 - 1 + ky, ix = ox * 2 - 1 + kx;
            bool ok = in && (unsigned)iy < (unsigned)IH && (unsigned)ix < (unsigned)IW;
            aptr[s] = ok ? (Abf + ((((size_t)bb * IH + iy) * IW + ix) << lgC) + ic_s + skoff)
                         : (g_zerow + ic_s + skoff);
        }
    }

    f32x4 acc[RM][RN];
    #pragma unroll
    for (int i = 0; i < RM; i++)
        #pragma unroll
        for (int j = 0; j < RN; j++) acc[i][j] = (f32x4){0.f, 0.f, 0.f, 0.f};

    for (int kb = k0; kb < kend; kb += 32) {
        #pragma unroll
        for (int s = 0; s < ACALLS; s++)
            gll16(aptr[s], &As[(size_t)(s * 64 + (wave << 4)) * 32]);
        #pragma unroll
        for (int s = 0; s < BCALLS; s++)
            gll16(bptr[s], &Bs[(size_t)(s * 64 + (wave << 4)) * 32]);
        // advance pointers (overlaps with load latency; drained by barrier)
        #pragma unroll
        for (int s = 0; s < BCALLS; s++) bptr[s] += bstep[s];
        if constexpr (MODE == 0) {
            #pragma unroll
            for (int s = 0; s < ACALLS; s++) aptr[s] += astep[s];
        } else {
            ic_s += 32;
            if (ic_s >= CIN) {               // block-uniform tap wrap
                ic_s = 0; tap_s++;
                if (tap_s < 9) {
                    int ky = tap_s / 3, kx = tap_s - (tap_s / 3) * 3;
                    #pragma unroll
                    for (int s = 0; s < ACALLS; s++) {
                        int iy = p_oy[s] * 2 - 1 + ky, ix = p_ox[s] * 2 - 1 + kx;
                        bool ok = p_in[s] && (unsigned)iy < (unsigned)IH && (unsigned)ix < (unsigned)IW;
                        aptr[s] = ok ? (Abf + ((((size_t)p_b[s] * IH + iy) * IW + ix) << lgC) + skoff)
                                     : (g_zerow + skoff);
                    }
                }
            } else {
                #pragma unroll
                for (int s = 0; s < ACALLS; s++) aptr[s] += 32;
            }
        }
        __syncthreads();
        bf16x8 af[RM], bfr[RN];
        #pragma unroll
        for (int i = 0; i < RM; i++)
            af[i] = *(const bf16x8*)&As[((wm * (BM / 2) + i * 16) >> 4) * 512 + quad * 128 + lm * 8];
        #pragma unroll
        for (int j = 0; j < RN; j++)
            bfr[j] = *(const bf16x8*)&Bs[((wn * (BN / 2) + j * 16) >> 4) * 512 + quad * 128 + lm * 8];
        #pragma unroll
        for (int i = 0; i < RM; i++)
            #pragma unroll
            for (int j = 0; j < RN; j++)
                acc[i][j] = __builtin_amdgcn_mfma_f32_16x16x32_bf16(af[i], bfr[j], acc[i][j], 0, 0, 0);
        __syncthreads();
    }

    const int n_base = nt * BN + wn * (BN / 2);
    const int m_base = mt * BM + wm * (BM / 2);
    int nj[RN]; float bvj[RN];
    #pragma unroll
    for (int j = 0; j < RN; j++) {
        nj[j] = n_base + j * 16 + lm;
        bvj[j] = 0.f;
        if (nj[j] < N && OUT != 4) {
            if (OUT == 0 || OUT == 5) bvj[j] = bias[nj[j]];
            else if (z == 0) bvj[j] = bias[nj[j]];
        }
    }
    if constexpr (OUT == 4) {
        float* op = (float*)outv;
        #pragma unroll
        for (int i = 0; i < RM; i++)
            #pragma unroll
            for (int r = 0; r < 4; r++) {
                int m = m_base + i * 16 + quad * 4 + r;
                if (m >= M) continue;
                #pragma unroll
                for (int j = 0; j < RN; j++)
                    if (nj[j] < N) atomicAdd(&op[(size_t)m * N + nj[j]], acc[i][j][r]);
            }
    } else if constexpr (OUT == 5) {
        u16* op = (u16*)outv;
        #pragma unroll
        for (int j = 0; j < RN; j++) {
            if (nj[j] >= N) continue;
            int c = nj[j] / 9, hw = nj[j] - c * 9;
            #pragma unroll
            for (int i = 0; i < RM; i++)
                #pragma unroll
                for (int r = 0; r < 4; r++) {
                    int m = m_base + i * 16 + quad * 4 + r;
                    if (m >= M) continue;
                    op[((size_t)m * 9 + hw) * 1024 + c] = f2bf(acc[i][j][r] + bvj[j]);
                }
        }
    } else if constexpr (OUT == 0) {
        int ohw = OH * OW;
        float sj[RN], qj[RN];
        #pragma unroll
        for (int j = 0; j < RN; j++) { sj[j] = 0.f; qj[j] = 0.f; }
        #pragma unroll
        for (int i = 0; i < RM; i++) {
            int m0 = m_base + i * 16 + quad * 4;
            if (m0 >= M) continue;
            int b = m0 / ohw, pix = m0 - b * ohw;  // ohw%4==0, m0%4==0 -> same image
            #pragma unroll
            for (int j = 0; j < RN; j++) {
                if (nj[j] >= N) continue;
                #pragma unroll
                for (int r = 0; r < 4; r++) {
                    float val = acc[i][j][r] + bvj[j];
                    ((u16*)outv)[((size_t)b * ohw + pix + r) * N + nj[j]] = f2bf(val);
                    if (STATS) {
                        float lv = val >= 0.f ? val : 0.01f * val;
                        sj[j] += lv; qj[j] += lv * lv;
                    }
                }
            }
        }
        if constexpr (STATS) {
            #pragma unroll
            for (int j = 0; j < RN; j++) {
                float s = sj[j], q = qj[j];
                s += __shfl_down(s, 32); q += __shfl_down(q, 32);
                s += __shfl_down(s, 16); q += __shfl_down(q, 16);
                if (quad == 0 && nj[j] < N) {
                    atomicAdd(&stat[nj[j]], s);
                    atomicAdd(&stat[N + nj[j]], q);
                }
            }
        }
    } else {  // OUT 1
        int ohw = OH * OW;
        #pragma unroll
        for (int i = 0; i < RM; i++) {
            int m0 = m_base + i * 16 + quad * 4;
            if (m0 >= M) continue;
            int b = m0 / ohw, pix = m0 - b * ohw;
            #pragma unroll
            for (int j = 0; j < RN; j++) {
                if (nj[j] >= N) continue;
                #pragma unroll
                for (int r = 0; r < 4; r++)
                    atomicAdd(&((float*)outv)[((size_t)b * ohw + pix + r) * N + nj[j]],
                              acc[i][j][r] + bvj[j]);
            }
        }
    }
}

// =========== all-class convT GEMM: grid.z = parity class ===========
template<int BM, int BN>
__global__ __launch_bounds__(256, 3)
void gemm_ct(const u16* __restrict__ Abf, const u16* __restrict__ Wb,
             const float* __restrict__ bias, u16* __restrict__ out,
             int N, int lgC, int IH, int IW, int OH, int OW,
             int4 Kc, int4 Mc, int4 Hc, int4 Wc, int4 Oc, int4 Dy, int4 Dx)
{
    constexpr int ACALLS = BM / 64, BCALLS = BN / 64;
    constexpr int RM = BM / 32, RN = BN / 32;
    const int c = blockIdx.z;
    const int Ks[4] = {Kc.x, Kc.y, Kc.z, Kc.w};
    const int Ms[4] = {Mc.x, Mc.y, Mc.z, Mc.w};
    const int Hs[4] = {Hc.x, Hc.y, Hc.z, Hc.w};
    const int Wsz[4]= {Wc.x, Wc.y, Wc.z, Wc.w};
    const int Os[4] = {Oc.x, Oc.y, Oc.z, Oc.w};
    const int Dys[4]= {Dy.x, Dy.y, Dy.z, Dy.w};
    const int Dxs[4]= {Dx.x, Dx.y, Dx.z, Dx.w};
    const int K = Ks[c], M = Ms[c], OHc = Hs[c], OWc = Wsz[c];
    const int dyp = Dys[c], dxp = Dxs[c];
    const int mt = blockIdx.x, nt = blockIdx.y;
    if (mt * BM >= M) return;
    const u16* Bw = Wb + Os[c];

    __shared__ __align__(16) u16 As[BM * 32];
    __shared__ __align__(16) u16 Bs[BN * 32];
    const int t = threadIdx.x;
    const int lane = t & 63, wave = t >> 6;
    const int lm = lane & 15, quad = lane >> 4;
    const int wm = wave & 1, wn = wave >> 1;

    const int sr16  = lane & 15;
    const int skoff = (lane >> 4) * 8;

    const u16* bptr[BCALLS];
    #pragma unroll
    for (int s = 0; s < BCALLS; s++) {
        int rg = nt * BN + s * 64 + (wave << 4) + sr16;   // OC multiple of BN
        bptr[s] = Bw + (size_t)rg * K + skoff;
    }

    const int ohwc = OHc * OWc;
    const int CIN = 1 << lgC;
    int p_b[ACALLS], p_oy[ACALLS], p_ox[ACALLS]; bool p_in[ACALLS];
    const u16* aptr[ACALLS];
    int ic_s = 0, ti_s = 0;
    {
        int dy = (int)(signed char)(dyp & 255);
        int dx = (int)(signed char)(dxp & 255);
        #pragma unroll
        for (int s = 0; s < ACALLS; s++) {
            int rg = mt * BM + s * 64 + (wave << 4) + sr16;
            bool in = rg < M;
            int g = in ? rg : 0;
            int bb = g / ohwc; int rr = g - bb * ohwc;
            int oy = rr / OWc, ox = rr - (rr / OWc) * OWc;
            p_in[s] = in; p_b[s] = bb; p_oy[s] = oy; p_ox[s] = ox;
            int iy = oy + dy, ix = ox + dx;
            bool ok = in && (unsigned)iy < (unsigned)IH && (unsigned)ix < (unsigned)IW;
            aptr[s] = ok ? (Abf + ((((size_t)bb * IH + iy) * IW + ix) << lgC) + skoff)
                         : (g_zerow + skoff);
        }
    }

    f32x4 acc[RM][RN];
    #pragma unroll
    for (int i = 0; i < RM; i++)
        #pragma unroll
        for (int j = 0; j < RN; j++) acc[i][j] = (f32x4){0.f, 0.f, 0.f, 0.f};

    for (int kb = 0; kb < K; kb += 32) {
        #pragma unroll
        for (int s = 0; s < ACALLS; s++)
            gll16(aptr[s], &As[(size_t)(s * 64 + (wave << 4)) * 32]);
        #pragma unroll
        for (int s = 0; s < BCALLS; s++)
            gll16(bptr[s], &Bs[(size_t)(s * 64 + (wave << 4)) * 32]);
        #pragma unroll
        for (int s = 0; s < BCALLS; s++) bptr[s] += 32;
        ic_s += 32;
        if (ic_s >= CIN) {               // block-uniform tap wrap
            ic_s = 0; ti_s++;
            int sh = 8 * (ti_s & 3);
            int dy = (int)(signed char)((dyp >> sh) & 255);
            int dx = (int)(signed char)((dxp >> sh) & 255);
            #pragma unroll
            for (int s = 0; s < ACALLS; s++) {
                int iy = p_oy[s] + dy, ix = p_ox[s] + dx;
                bool ok = p_in[s] && (unsigned)iy < (unsigned)IH && (unsigned)ix < (unsigned)IW;
                aptr[s] = ok ? (Abf + ((((size_t)p_b[s] * IH + iy) * IW + ix) << lgC) + skoff)
                             : (g_zerow + skoff);
            }
        } else {
            #pragma unroll
            for (int s = 0; s < ACALLS; s++) aptr[s] += 32;
        }
        __syncthreads();
        bf16x8 af[RM], bfr[RN];
        #pragma unroll
        for (int i = 0; i < RM; i++)
            af[i] = *(const bf16x8*)&As[((wm * (BM / 2) + i * 16) >> 4) * 512 + quad * 128 + lm * 8];
        #pragma unroll
        for (int j = 0; j < RN; j++)
            bfr[j] = *(const bf16x8*)&Bs[((wn * (BN / 2) + j * 16) >> 4) * 512 + quad * 128 + lm * 8];
        #pragma unroll
        for (int i = 0; i < RM; i++)
            #pragma unroll
            for (int j = 0; j < RN; j++)
                acc[i][j] = __builtin_amdgcn_mfma_f32_16x16x32_bf16(af[i], bfr[j], acc[i][j], 0, 0, 0);
        __syncthreads();
    }

    const int n_base = nt * BN + wn * (BN / 2);
    const int m_base = mt * BM + wm * (BM / 2);
    const int cy = c >> 1, cx = c & 1;
    const int OHW = OH * OW;
    int nj[RN]; float bvj[RN];
    #pragma unroll
    for (int j = 0; j < RN; j++) {
        nj[j] = n_base + j * 16 + lm;
        bvj[j] = (nj[j] < N) ? bias[nj[j]] : 0.f;
    }
    #pragma unroll
    for (int i = 0; i < RM; i++)
        #pragma unroll
        for (int r = 0; r < 4; r++) {
            int m = m_base + i * 16 + quad * 4 + r;
            if (m >= M) continue;
            int b = m / ohwc, r2 = m - b * ohwc;
            int oyc = r2 / OWc, oxc = r2 - (r2 / OWc) * OWc;
            size_t ad0 = ((size_t)b * OHW + (2 * oyc + cy) * OW + 2 * oxc + cx) * N;
            #pragma unroll
            for (int j = 0; j < RN; j++)
                if (nj[j] < N) out[ad0 + nj[j]] = f2bf(acc[i][j][r] + bvj[j]);
        }
}

// ===================== weight prep =====================
// per-oc LDS transpose: src [OC][CIN][9] f32 (coalesced read) ->
// dst [OC][tap][CIN] bf16 (coalesced write)
__global__ __launch_bounds__(256)
void convw_prep(const float* __restrict__ src, u16* __restrict__ dst, int lgC) {
    __shared__ float tl[9216];
    int CIN = 1 << lgC;
    int n = CIN * 9;
    size_t base = (size_t)blockIdx.x * n;
    for (int i = threadIdx.x; i < n; i += 256) tl[i] = src[base + i];
    __syncthreads();
    for (int j = threadIdx.x; j < n; j += 256) {
        int tap = j >> lgC, ic = j & (CIN - 1);
        dst[base + j] = f2bf(tl[ic * 9 + tap]);
    }
}

__global__ __launch_bounds__(256)
void transpose_cvt(const float* __restrict__ in, u16* __restrict__ out, int R, int C) {
    __shared__ float tl[32][33];
    int c0 = blockIdx.x * 32, r0 = blockIdx.y * 32;
    int tx = threadIdx.x & 31, ty = threadIdx.x >> 5;
    #pragma unroll
    for (int l = 0; l < 4; l++)
        tl[ty + 8 * l][tx] = in[(size_t)(r0 + ty + 8 * l) * C + c0 + tx];
    __syncthreads();
    #pragma unroll
    for (int l = 0; l < 4; l++)
        out[(size_t)(c0 + ty + 8 * l) * R + r0 + tx] = f2bf(tl[tx][ty + 8 * l]);
}

// fused transpose + parity-class gather for convT weights:
// in  = [CIN][OC*9] f32 (ic-major, as given)
// out = per class cls: off[cls] + oc*K[cls] + ti*CIN + ic  (bf16)
__global__ __launch_bounds__(256)
void ctw_fused(const float* __restrict__ in, u16* __restrict__ outw,
               int CIN, int P, int4 Kc, int4 Oc) {
    __shared__ float tl[32][33];
    int c0 = blockIdx.x * 32, r0 = blockIdx.y * 32;
    int C = gridDim.x * 32;                       // = OC*9
    int tx = threadIdx.x & 31, ty = threadIdx.x >> 5;
    #pragma unroll
    for (int l = 0; l < 4; l++)
        tl[ty + 8 * l][tx] = in[(size_t)(r0 + ty + 8 * l) * C + c0 + tx];
    __syncthreads();
    const int Ks[4] = {Kc.x, Kc.y, Kc.z, Kc.w};
    const int Os[4] = {Oc.x, Oc.y, Oc.z, Oc.w};
    int ic = r0 + tx;
    #pragma unroll
    for (int l = 0; l < 4; l++) {
        int cc = c0 + ty + 8 * l;
        int oc = cc / 9, tap = cc - 9 * oc;
        int ky = tap / 3, kx = tap - 3 * (tap / 3);
        int cyc = (P + ky) & 1, cxc = (P + kx) & 1;
        int cls = cyc * 2 + cxc;
        int nkx = ((P ^ cxc) & 1) ? 1 : 2;
        int ti = (ky >> 1) * nkx + (kx >> 1);
        outw[Os[cls] + (size_t)oc * Ks[cls] + ti * CIN + ic] = f2bf(tl[tx][ty + 8 * l]);
    }
}

__global__ __launch_bounds__(256)
void fcw_prep(const float* __restrict__ in, u16* __restrict__ out) {
    __shared__ float tl[32][33];
    int n0 = blockIdx.x * 32, c0 = blockIdx.y * 32, hw = blockIdx.z;
    int tx = threadIdx.x & 31, ty = threadIdx.x >> 5;
    #pragma unroll
    for (int l = 0; l < 4; l++)
        tl[ty + 8 * l][tx] = in[((size_t)(c0 + ty + 8 * l) * 16 + hw) * 800 + n0 + tx];
    __syncthreads();
    #pragma unroll
    for (int l = 0; l < 4; l++)
        out[(size_t)(n0 + ty + 8 * l) * 16384 + hw * 1024 + c0 + tx] = f2bf(tl[tx][ty + 8 * l]);
}

__global__ __launch_bounds__(256)
void wt5_prep(const float* __restrict__ in, u16* __restrict__ out) {
    int idx = blockIdx.x * 256 + threadIdx.x;
    if (idx >= 576) return;
    int tap = idx >> 6, ic = idx & 63;
    out[idx] = f2bf(in[ic * 9 + tap]);
}

// ===================== non-GEMM =====================
__global__ __launch_bounds__(256)
void conv1_nhwc(const float* __restrict__ x, const float* __restrict__ w,
                const float* __restrict__ bias, u16* __restrict__ out) {
    int idx = blockIdx.x * 256 + threadIdx.x;
    if (idx >= 100 * 1024 * 128) return;
    int oc = idx & 127;
    int pix = (idx >> 7) & 1023;
    int b = idx >> 17;
    int oy = pix >> 5, ox = pix & 31;
    int iy0 = oy * 2 - 1, ix0 = ox * 2 - 1;
    float acc = bias[oc];
    const float* ip = x + (size_t)b * 4096;
    const float* wp = w + oc * 9;
    #pragma unroll
    for (int ky = 0; ky < 3; ky++) {
        int iy = iy0 + ky;
        if ((unsigned)iy >= 64u) continue;
        #pragma unroll
        for (int kx = 0; kx < 3; kx++) {
            int ix = ix0 + kx;
            if ((unsigned)ix >= 64u) continue;
            acc = fmaf(ip[iy * 64 + ix], wp[ky * 3 + kx], acc);
        }
    }
    out[idx] = f2bf(acc);
}

// vectorized bf16x8 BN stats (leaky applied); LDS-staged partials
__global__ __launch_bounds__(256)
void bnstat8(const u16* __restrict__ x, float* __restrict__ accum, int C, int total) {
    __shared__ float ls[2048];
    for (int i = threadIdx.x; i < 2 * C; i += 256) ls[i] = 0.f;
    __syncthreads();
    int base = (blockIdx.x * 256 + threadIdx.x) * 8;
    int stride = gridDim.x * 256 * 8;
    float s[8], q[8];
    #pragma unroll
    for (int r = 0; r < 8; r++) { s[r] = 0.f; q[r] = 0.f; }
    for (int i = base; i < total; i += stride) {
        uint4 v = *(const uint4*)(x + i);
        const unsigned* w = (const unsigned*)&v;
        #pragma unroll
        for (int h = 0; h < 4; h++) {
            float v0 = __builtin_bit_cast(float, w[h] << 16);
            float v1 = __builtin_bit_cast(float, w[h] & 0xFFFF0000u);
            v0 = v0 >= 0.f ? v0 : 0.01f * v0;
            v1 = v1 >= 0.f ? v1 : 0.01f * v1;
            s[2 * h] += v0;     q[2 * h] += v0 * v0;
            s[2 * h + 1] += v1; q[2 * h + 1] += v1 * v1;
        }
    }
    int c0 = base & (C - 1);
    #pragma unroll
    for (int r = 0; r < 8; r++) {
        atomicAdd(&ls[c0 + r], s[r]);
        atomicAdd(&ls[C + c0 + r], q[r]);
    }
    __syncthreads();
    for (int i = threadIdx.x; i < 2 * C; i += 256) atomicAdd(&accum[i], ls[i]);
}

// vectorized bf16x8 BN apply (leaky + normalize), in-place safe
__global__ __launch_bounds__(256)
void bnapply8(const u16* __restrict__ x, u16* __restrict__ out,
              const float* __restrict__ accum, int C, int total, float invcnt) {
    int i8 = (blockIdx.x * 256 + threadIdx.x) * 8;
    if (i8 >= total) return;
    int c0 = i8 & (C - 1);
    uint4 v = *(const uint4*)(x + i8);
    const unsigned* w = (const unsigned*)&v;
    uint4 o;
    unsigned* ow = (unsigned*)&o;
    #pragma unroll
    for (int h = 0; h < 4; h++) {
        float m0 = accum[c0 + 2 * h] * invcnt, m1 = accum[c0 + 2 * h + 1] * invcnt;
        float q0 = accum[C + c0 + 2 * h] * invcnt, q1 = accum[C + c0 + 2 * h + 1] * invcnt;
        float in0 = rsqrtf(q0 - m0 * m0 + 1e-5f);
        float in1 = rsqrtf(q1 - m1 * m1 + 1e-5f);
        float v0 = __builtin_bit_cast(float, w[h] << 16);
        float v1 = __builtin_bit_cast(float, w[h] & 0xFFFF0000u);
        v0 = v0 >= 0.f ? v0 : 0.01f * v0;
        v1 = v1 >= 0.f ? v1 : 0.01f * v1;
        unsigned r0 = f2bf((v0 - m0) * in0);
        unsigned r1 = f2bf((v1 - m1) * in1);
        ow[h] = r0 | (r1 << 16);
    }
    *(uint4*)(out + i8) = o;
}

// f32 x4 variants (conv4 split-K accumulator path)
__global__ __launch_bounds__(256)
void bnstat4f(const float* __restrict__ x, float* __restrict__ accum, int C, int total) {
    __shared__ float ls[2048];
    for (int i = threadIdx.x; i < 2 * C; i += 256) ls[i] = 0.f;
    __syncthreads();
    int base = (blockIdx.x * 256 + threadIdx.x) * 4;
    int stride = gridDim.x * 1024;
    float s[4] = {0, 0, 0, 0}, q[4] = {0, 0, 0, 0};
    for (int i = base; i < total; i += stride) {
        f32x4 v = *(const f32x4*)(x + i);
        #pragma unroll
        for (int r = 0; r < 4; r++) {
            float vv = v[r]; vv = vv >= 0.f ? vv : 0.01f * vv;
            s[r] += vv; q[r] += vv * vv;
        }
    }
    int c0 = base & (C - 1);
    #pragma unroll
    for (int r = 0; r < 4; r++) {
        atomicAdd(&ls[c0 + r], s[r]);
        atomicAdd(&ls[C + c0 + r], q[r]);
    }
    __syncthreads();
    for (int i = threadIdx.x; i < 2 * C; i += 256) atomicAdd(&accum[i], ls[i]);
}

__global__ __launch_bounds__(256)
void bnapply4f(const float* __restrict__ x, u16* __restrict__ out,
               const float* __restrict__ accum, int C, int total, float invcnt) {
    int i4 = (blockIdx.x * 256 + threadIdx.x) * 4;
    if (i4 >= total) return;
    int c0 = i4 & (C - 1);
    f32x4 v = *(const f32x4*)(x + i4);
    unsigned r4[4];
    #pragma unroll
    for (int r = 0; r < 4; r++) {
        float m = accum[c0 + r] * invcnt;
        float var = accum[C + c0 + r] * invcnt - m * m;
        float inv = rsqrtf(var + 1e-5f);
        float vv = v[r]; vv = vv >= 0.f ? vv : 0.01f * vv;
        r4[r] = f2bf((vv - m) * inv);
    }
    *(uint2*)(out + i4) = make_uint2(r4[0] | (r4[1] << 16), r4[2] | (r4[3] << 16));
}

// fused: relu(facc+bias) -> eig (output) + DFT rows (replaces finalize_relu)
__global__ __launch_bounds__(256)
void dft_real(const float* __restrict__ facc, const float* __restrict__ fcb,
              float* __restrict__ eig, float* __restrict__ Yr, u16* __restrict__ Yrb) {
    __shared__ float se[800];
    __shared__ float ctab[800];
    int b = blockIdx.x;
    for (int i = threadIdx.x; i < 800; i += 256) {
        float v = fmaxf(facc[b * 800 + i] + fcb[i], 0.f);
        se[i] = v;
        if (blockIdx.y == 0) eig[b * 800 + i] = v;
        ctab[i] = cospif(i * 0.0025f);   // cos(2*pi*i/800)
    }
    __syncthreads();
    int o0 = blockIdx.y * 400;
    for (int oi = o0 + threadIdx.x; oi < o0 + 400; oi += 256) {
        int k1 = oi >> 3, k2 = oi & 7;
        int d1 = k1 * 8, d2 = k2 * 100;
        float acc0 = 0.f, acc1 = 0.f;
        int p1 = 0;
        for (int n1 = 0; n1 < 100; n1 += 2) {
            int p = p1;
            #pragma unroll
            for (int n2 = 0; n2 < 8; n2++) {
                acc0 = fmaf(se[n1 * 8 + n2], ctab[p], acc0);
                p += d2; if (p >= 800) p -= 800;
            }
            int pb = p1 + d1; if (pb >= 800) pb -= 800;
            int p2 = pb;
            #pragma unroll
            for (int n2 = 0; n2 < 8; n2++) {
                acc1 = fmaf(se[(n1 + 1) * 8 + n2], ctab[p2], acc1);
                p2 += d2; if (p2 >= 800) p2 -= 800;
            }
            p1 = pb + d1; if (p1 >= 800) p1 -= 800;
        }
        float acc = acc0 + acc1;
        Yr[b * 800 + oi] = acc;
        Yrb[b * 800 + oi] = f2bf(acc);
    }
}

__global__ __launch_bounds__(256)
void build_C4(const float* __restrict__ Yr, float* __restrict__ C) {
    int idx = blockIdx.x * 256 + threadIdx.x;
    if (idx >= 100 * 800 * 200) return;
    int j4 = (idx % 200) * 4; int tt = idx / 200;
    int i = tt % 800;         int b = tt / 800;
    const float* y = Yr + b * 800;
    f32x4 v;
    #pragma unroll
    for (int r = 0; r < 4; r++) {
        int k = i - (j4 + r);
        k += (k >> 31) & 800;
        v[r] = y[k] * 0.035355339059327376f;
    }
    ((f32x4*)C)[idx] = v;
}

__global__ __launch_bounds__(256)
void convT5(const u16* __restrict__ in, const u16* __restrict__ w,
            const float* __restrict__ bias, float* __restrict__ out) {
    int idx = blockIdx.x * 256 + threadIdx.x;
    if (idx >= 100 * 49 * 49) return;
    int ox = idx % 49; int t2 = idx / 49;
    int oy = t2 % 49;  int b = t2 / 49;
    float ac[8];
    #pragma unroll
    for (int r = 0; r < 8; r++) ac[r] = 0.f;
    for (int ky = 0; ky < 3; ky++) {
        int iy = oy - ky;
        if ((unsigned)iy >= 47u) continue;
        for (int kx = 0; kx < 3; kx++) {
            int ix = ox - kx;
            if ((unsigned)ix >= 47u) continue;
            const uint4* ip = (const uint4*)(in + (((size_t)b * 47 + iy) * 47 + ix) * 64);
            const uint4* wp = (const uint4*)(w + (ky * 3 + kx) * 64);
            #pragma unroll
            for (int g = 0; g < 8; g++) {
                uint4 av = ip[g], wv = wp[g];
                const unsigned* aa = (const unsigned*)&av;
                const unsigned* ww = (const unsigned*)&wv;
                #pragma unroll
                for (int h = 0; h < 4; h++) {
                    float a0 = __builtin_bit_cast(float, aa[h] << 16);
                    float a1 = __builtin_bit_cast(float, aa[h] & 0xFFFF0000u);
                    float w0 = __builtin_bit_cast(float, ww[h] << 16);
                    float w1 = __builtin_bit_cast(float, ww[h] & 0xFFFF0000u);
                    int rix = ((g & 1) << 2) | h;   // 8 independent chains
                    ac[rix] = fmaf(a0, w0, ac[rix]);
                    ac[rix] = fmaf(a1, w1, ac[rix]);
                }
            }
        }
    }
    out[idx] = bias[0] + ((ac[0] + ac[1]) + (ac[2] + ac[3]))
                       + ((ac[4] + ac[5]) + (ac[6] + ac[7]));
}

// ===================== host helpers =====================
struct CTClass { int T, OHc, OWc, dyp, dxp, off, K; };
static void ct_params(int P, int OH, int OW, int CIN, int OC, CTClass cls[4]) {
    int off = 0;
    for (int c = 0; c < 4; c++) {
        int cy = c >> 1, cx = c & 1;
        int kys[2], dys[2], nky = 0, kxs[2], dxs[2], nkx = 0;
        for (int ky = 0; ky < 3; ky++)
            if (((cy + P + ky) & 1) == 0) { kys[nky] = ky; dys[nky] = (cy + P - ky) / 2; nky++; }
        for (int kx = 0; kx < 3; kx++)
            if (((cx + P + kx) & 1) == 0) { kxs[nkx] = kx; dxs[nkx] = (cx + P - kx) / 2; nkx++; }
        CTClass& cc = cls[c];
        cc.T = nky * nkx;
        cc.OHc = (OH - cy + 1) >> 1; cc.OWc = (OW - cx + 1) >> 1;
        cc.dyp = 0; cc.dxp = 0;
        int ti = 0;
        for (int a = 0; a < nky; a++)
            for (int b2 = 0; b2 < nkx; b2++, ti++) {
                cc.dyp |= (dys[a] & 255) << (8 * ti);
                cc.dxp |= (dxs[b2] & 255) << (8 * ti);
            }
        cc.off = off; cc.K = CIN * cc.T;
        off += OC * cc.K;
    }
}

template<int BM, int BN>
static void launch_ct(hipStream_t s, const u16* in, const u16* W, const float* bias, u16* outp,
                      int lgC, int OC, int IH, int IW, int OH, int OW, const CTClass* cls) {
    int maxMT = 0;
    for (int c = 0; c < 4; c++) {
        int mt = (100 * cls[c].OHc * cls[c].OWc + BM - 1) / BM;
        if (mt > maxMT) maxMT = mt;
    }
    dim3 g(maxMT, OC / BN, 4);
    gemm_ct<BM, BN><<<g, 256, 0, s>>>(in, W, bias, outp, OC, lgC, IH, IW, OH, OW,
        make_int4(cls[0].K, cls[1].K, cls[2].K, cls[3].K),
        make_int4(100*cls[0].OHc*cls[0].OWc, 100*cls[1].OHc*cls[1].OWc,
                  100*cls[2].OHc*cls[2].OWc, 100*cls[3].OHc*cls[3].OWc),
        make_int4(cls[0].OHc, cls[1].OHc, cls[2].OHc, cls[3].OHc),
        make_int4(cls[0].OWc, cls[1].OWc, cls[2].OWc, cls[3].OWc),
        make_int4(cls[0].off, cls[1].off, cls[2].off, cls[3].off),
        make_int4(cls[0].dyp, cls[1].dyp, cls[2].dyp, cls[3].dyp),
        make_int4(cls[0].dxp, cls[1].dxp, cls[2].dxp, cls[3].dxp));
}

static void launch_ctw(hipStream_t s, const float* w, u16* outw,
                       int CIN, int OC, int P, const CTClass* cls) {
    dim3 g((OC * 9) / 32, CIN / 32);
    ctw_fused<<<g, 256, 0, s>>>(w, outw, CIN, P,
        make_int4(cls[0].K, cls[1].K, cls[2].K, cls[3].K),
        make_int4(cls[0].off, cls[1].off, cls[2].off, cls[3].off));
}

extern "C" void kernel_launch(void* const* d_in, const int* in_sizes, int n_in,
                              void* d_out, int out_size, void* d_ws, size_t ws_size,
                              hipStream_t stream) {
    const float* x    = (const float*)d_in[0];
    const float* c1w  = (const float*)d_in[1];  const float* c1b = (const float*)d_in[2];
    const float* c2w  = (const float*)d_in[3];  const float* c2b = (const float*)d_in[4];
    const float* c3w  = (const float*)d_in[5];  const float* c3b = (const float*)d_in[6];
    const float* c4w  = (const float*)d_in[7];  const float* c4b = (const float*)d_in[8];
    const float* fcw  = (const float*)d_in[9];  const float* fcb = (const float*)d_in[10];
    const float* decw = (const float*)d_in[11]; const float* decb = (const float*)d_in[12];
    const float* t1w  = (const float*)d_in[13]; const float* t1b = (const float*)d_in[14];
    const float* t2w  = (const float*)d_in[15]; const float* t2b = (const float*)d_in[16];
    const float* t3w  = (const float*)d_in[17]; const float* t3b = (const float*)d_in[18];
    const float* t4w  = (const float*)d_in[19]; const float* t4b = (const float*)d_in[20];
    const float* t5w  = (const float*)d_in[21]; const float* t5b = (const float*)d_in[22];

    float* out = (float*)d_out;
    float* d_final = out;
    float* Cmat    = out + 240100;
    float* eig     = out + 240100 + 64000000;

    float* ws = (float*)d_ws;
    // ---- encoder-phase workspace (float units) ----
    u16*   h1    = (u16*)(ws);                 // 13,107,200 bf16
    u16*   W_fc  = (u16*)(ws);                 // reuse @0 after conv2
    u16*   h2    = (u16*)(ws + 6553600);
    u16*   h3    = (u16*)(ws + 9830400);
    u16*   W_c2  = (u16*)(ws + 13107200);
    u16*   W_c3  = (u16*)(ws + 13254656);
    u16*   W_c4  = (u16*)(ws + 14434304);
    float* h4f   = ws + 19152896;              // 1,638,400 f32
    u16*   h4    = (u16*)(ws + 20791296);
    float* accs  = ws + 21610496;              // 8,192 f32 (4 layer slices)
    float* facc  = ws + 21618688;              // 80,000 f32
    float* Yr    = ws + 21698688;              // 80,000 f32
    u16*   Yrb   = (u16*)(ws + 21778688);      // 80,000 bf16
    u16*   d0    = (u16*)(ws + 21818688);      // 921,600 bf16
    u16*   W_dec = (u16*)(ws + 22279488);      // 7,372,800 bf16 -> ends 25,965,888
    float* acc1 = accs, *acc2 = accs + 2048, *acc3 = accs + 4096, *acc4 = accs + 6144;
    // ---- decoder-phase (encoder region dead) ----
    u16*   W_t   = (u16*)(ws);                 // up to 4,718,592 bf16
    u16*   o1    = (u16*)(ws + 4718592);       // 1,280,000 bf16
    u16*   o2    = (u16*)(ws + 5358592);       // 3,097,600 bf16
    u16*   o3    = (u16*)(ws + 6907392);       // 6,771,200 bf16
    u16*   o4    = (u16*)(ws + 10292992);      // 14,137,600 bf16
    u16*   W_t5  = (u16*)(ws + 17361792);

    #define GRID(n) dim3(((n) + 255) / 256)

    // clear all BN-stat slices + facc in one fill
    hipMemsetAsync(accs, 0, (8192 + 80000) * 4, stream);

    // ======== encoder ========
    conv1_nhwc<<<GRID(13107200), 256, 0, stream>>>(x, c1w, c1b, h1);
    bnstat8<<<1024, 256, 0, stream>>>(h1, acc1, 128, 13107200);
    bnapply8<<<GRID(1638400), 256, 0, stream>>>(h1, h1, acc1, 128, 13107200, 1.f / 102400.f);

    convw_prep<<<dim3(256), 256, 0, stream>>>(c2w, W_c2, 7);
    gemm<1, 0, 128, 128, 0, true><<<dim3(200, 2, 1), 256, 0, stream>>>(
        h1, W_c2, c2b, h2, acc2, 25600, 256, 1152, 7, 32, 32, 16, 16, 1152);
    bnapply8<<<GRID(819200), 256, 0, stream>>>(h2, h2, acc2, 256, 6553600, 1.f / 25600.f);

    convw_prep<<<dim3(1024), 256, 0, stream>>>(c3w, W_c3, 8);
    gemm<1, 0, 128, 128, 1, true><<<dim3(400, 1, 1), 256, 0, stream>>>(
        h2, W_c3, c3b, h3, acc3, 6400, 1024, 2304, 8, 16, 16, 8, 8, 2304);
    bnapply8<<<GRID(819200), 256, 0, stream>>>(h3, h3, acc3, 1024, 6553600, 1.f / 6400.f);

    convw_prep<<<dim3(1024), 256, 0, stream>>>(c4w, W_c4, 10);
    hipMemsetAsync(h4f, 0, 1638400 * 4, stream);
    gemm<1, 1, 64, 128, 1, false><<<dim3(400, 1, 1), 256, 0, stream>>>(
        h3, W_c4, c4b, h4f, nullptr, 1600, 1024, 9216, 10, 8, 8, 4, 4, 4608);
    bnstat4f<<<1024, 256, 0, stream>>>(h4f, acc4, 1024, 1638400);
    bnapply4f<<<GRID(409600), 256, 0, stream>>>(h4f, h4, acc4, 1024, 1638400, 1.f / 1600.f);

    // ======== fc (split-K z=16) ========
    fcw_prep<<<dim3(25, 32, 16), 256, 0, stream>>>(fcw, W_fc);
    gemm<0, 4, 64, 64, 0, false><<<dim3(2, 13, 16), 256, 0, stream>>>(
        h4, W_fc, nullptr, facc, nullptr, 100, 800, 16384, 0, 0, 0, 0, 0, 1024);

    // ======== FFT block (relu fused into dft) ========
    dft_real<<<dim3(100, 2), 256, 0, stream>>>(facc, fcb, eig, Yr, Yrb);
    build_C4<<<GRID(16000000), 256, 0, stream>>>(Yr, Cmat);

    // ======== dec matmul ========
    transpose_cvt<<<dim3(288, 25), 256, 0, stream>>>(decw, W_dec, 800, 9216);
    gemm<0, 5, 64, 64, 0, false><<<dim3(2, 144, 1), 256, 0, stream>>>(
        Yrb, W_dec, decb, d0, nullptr, 100, 9216, 800, 0, 0, 0, 0, 0, 800);

    // ======== decoder convT stack ========
    CTClass c1c[4], c2c[4], c3c[4], c4c[4];
    ct_params(1, 5, 5, 1024, 512, c1c);
    ct_params(0, 11, 11, 512, 256, c2c);
    ct_params(0, 23, 23, 256, 128, c3c);
    ct_params(0, 47, 47, 128, 64, c4c);

    launch_ctw(stream, t1w, W_t, 1024, 512, 1, c1c);
    launch_ct<64, 64>(stream, d0, W_t, t1b, o1, 10, 512, 3, 3, 5, 5, c1c);

    launch_ctw(stream, t2w, W_t, 512, 256, 0, c2c);
    launch_ct<64, 128>(stream, o1, W_t, t2b, o2, 9, 256, 5, 5, 11, 11, c2c);

    launch_ctw(stream, t3w, W_t, 256, 128, 0, c3c);
    launch_ct<64, 128>(stream, o2, W_t, t3b, o3, 8, 128, 11, 11, 23, 23, c3c);

    launch_ctw(stream, t4w, W_t, 128, 64, 0, c4c);
    launch_ct<128, 64>(stream, o3, W_t, t4b, o4, 7, 64, 23, 23, 47, 47, c4c);

    wt5_prep<<<GRID(576), 256, 0, stream>>>(t5w, W_t5);
    convT5<<<GRID(240100), 256, 0, stream>>>(o4, W_t5, t5b, d_final);

    #undef GRID
}

// Round 5
// 1075.246 us; speedup vs baseline: 1.1089x; 1.1089x over previous
//
#include <hip/hip_runtime.h>
#include <math.h>

typedef __attribute__((ext_vector_type(8))) short bf16x8;
typedef __attribute__((ext_vector_type(4))) float f32x4;
typedef unsigned short u16;

__device__ __forceinline__ u16 f2bf(float f) {
    unsigned u = __builtin_bit_cast(unsigned, f);
    u += 0x7FFFu + ((u >> 16) & 1u);   // RNE
    return (u16)(u >> 16);
}
__device__ __forceinline__ float bf2f(u16 h) {
    unsigned u = ((unsigned)h) << 16;
    return __builtin_bit_cast(float, u);
}

// =====================================================================
// MFMA GEMM — reg-staged (global->VGPR->LDS) with one-tile register
// prefetch (PF): loads for tile k+1 issue before tile k's MFMA, hiding
// memory latency intra-wave (critical at our ~1.5 blocks/CU occupancy;
// global_load_lds regressed here — round-4 lesson).
// MODE 0: A = bf16 [M][K] rows            (fc, dec)
// MODE 1: A = im2col of bf16 NHWC input, conv3x3 s2 p1; k = tap*CIN+ic
//         (incremental: tap/bounds/base recomputed only on ic wrap)
// OUT  0: bf16 NHWC conv (+bias; optional fused BN stats)
// OUT  1: fp32 atomic NHWC conv (+bias at z==0)
// OUT  4: fp32 atomic plain (no bias)
// OUT  6: bf16 direct [m][N] rows, bias under dec-permutation
//         (B rows pre-permuted n' = (n%9)*1024 + n/9 -> coalesced writes)
// SWIZ 1: 1D grid, nt = id&7 (requires N/BN == 8) -> per-XCD weight L2 reuse
// =====================================================================
template<int MODE, int OUT, int BM, int BN, int SWIZ, bool STATS, bool PF>
__global__ __launch_bounds__(256, 3)
void gemm(const u16* __restrict__ Abf, const u16* __restrict__ Bw,
          const float* __restrict__ bias, void* __restrict__ outv,
          float* __restrict__ stat,
          int M, int N, int K, int lgC,
          int IH, int IW, int OH, int OW, int zchunk)
{
    constexpr int ANSEG = BM / 64, BNSEG = BN / 64;
    constexpr int RM = BM / 32, RN = BN / 32;
    __shared__ __align__(16) u16 As[4 * BM * 8];
    __shared__ __align__(16) u16 Bs[4 * BN * 8];
    const int t = threadIdx.x;
    const int lane = t & 63, wave = t >> 6;
    const int lm = lane & 15, quad = lane >> 4;
    const int wm = wave & 1, wn = wave >> 1;
    int mt, nt, z;
    if (SWIZ == 1) {
        int mtN = (M + BM - 1) / BM;
        int id = blockIdx.x;
        nt = id & 7; int j = id >> 3;
        mt = j % mtN; z = j / mtN;
    } else { mt = blockIdx.x; nt = blockIdx.y; z = blockIdx.z; }
    const int k0 = z * zchunk, kend = k0 + zchunk;

    const int arow = (ANSEG == 2) ? (t >> 1) : (t >> 2);
    const int akb  = (ANSEG == 2) ? (t & 1) * 16 : (t & 3) * 8;
    const int a_gm = mt * BM + arow;
    const bool a_in = a_gm < M;
    int oy = 0, ox = 0, bimg = 0;
    if (MODE == 1) {
        int ohw = OH * OW;
        int g = a_in ? a_gm : 0;
        bimg = g / ohw; int r = g - bimg * ohw;
        oy = r / OW; ox = r - (r / OW) * OW;
    }
    const int brow = (BNSEG == 2) ? (t >> 1) : (t >> 2);
    const int bkb  = (BNSEG == 2) ? (t & 1) * 16 : (t & 3) * 8;
    const int b_gn = nt * BN + brow;
    const bool b_in = b_gn < N;

    // ---- incremental A state ----
    const int Cmask = (1 << lgC) - 1;
    int ic_s = 0, tap_s = 0;
    bool aok = a_in;
    const u16* aptr;
    if (MODE == 0) {
        aptr = Abf + (size_t)a_gm * K + k0 + akb;
    } else {
        int kk0 = k0 + akb;
        tap_s = kk0 >> lgC; ic_s = kk0 & Cmask;
        int ky = tap_s / 3, kx = tap_s - (tap_s / 3) * 3;
        int iy = oy * 2 - 1 + ky, ix = ox * 2 - 1 + kx;
        aok = a_in && (unsigned)iy < (unsigned)IH && (unsigned)ix < (unsigned)IW;
        aptr = Abf + ((((size_t)bimg * IH + iy) * IW + ix) << lgC);
    }
    const u16* bptr = Bw + (size_t)b_gn * K + k0 + bkb;

    auto ldA = [&](uint4 (&v)[ANSEG]) {
        #pragma unroll
        for (int s = 0; s < ANSEG; s++) {
            uint4 x4 = make_uint4(0, 0, 0, 0);
            if (MODE == 0) {
                if (aok) x4 = *(const uint4*)(aptr + s * 8);
            } else {
                if (aok) x4 = *(const uint4*)(aptr + ic_s + s * 8);
            }
            v[s] = x4;
        }
        if (MODE == 0) {
            aptr += 32;
        } else {
            ic_s += 32;
            if (ic_s > Cmask) {            // block-uniform wrap
                ic_s -= Cmask + 1;
                tap_s++;
                int ky = tap_s / 3, kx = tap_s - (tap_s / 3) * 3;
                int iy = oy * 2 - 1 + ky, ix = ox * 2 - 1 + kx;
                aok = a_in && (unsigned)iy < (unsigned)IH && (unsigned)ix < (unsigned)IW;
                aptr = Abf + ((((size_t)bimg * IH + iy) * IW + ix) << lgC);
            }
        }
    };
    auto ldB = [&](uint4 (&v)[BNSEG]) {
        #pragma unroll
        for (int s = 0; s < BNSEG; s++) {
            uint4 x4 = make_uint4(0, 0, 0, 0);
            if (b_in) x4 = *(const uint4*)(bptr + s * 8);
            v[s] = x4;
        }
        bptr += 32;
    };

    f32x4 acc[RM][RN];
    #pragma unroll
    for (int i = 0; i < RM; i++)
        #pragma unroll
        for (int j = 0; j < RN; j++) acc[i][j] = (f32x4){0.f, 0.f, 0.f, 0.f};

    uint4 va[ANSEG], vb[BNSEG];
    if (PF) { ldA(va); ldB(vb); }
    for (int kb = k0; kb < kend; kb += 32) {
        if (!PF) { ldA(va); ldB(vb); }
        #pragma unroll
        for (int s = 0; s < ANSEG; s++)
            *(uint4*)&As[(((akb >> 3) + s) * BM + arow) * 8] = va[s];
        #pragma unroll
        for (int s = 0; s < BNSEG; s++)
            *(uint4*)&Bs[(((bkb >> 3) + s) * BN + brow) * 8] = vb[s];
        __syncthreads();
        if (PF && kb + 32 < kend) { ldA(va); ldB(vb); }
        bf16x8 af[RM], bfr[RN];
        #pragma unroll
        for (int i = 0; i < RM; i++)
            af[i] = *(const bf16x8*)&As[(size_t)(quad * BM + wm * (BM / 2) + i * 16 + lm) * 8];
        #pragma unroll
        for (int j = 0; j < RN; j++)
            bfr[j] = *(const bf16x8*)&Bs[(size_t)(quad * BN + wn * (BN / 2) + j * 16 + lm) * 8];
        #pragma unroll
        for (int i = 0; i < RM; i++)
            #pragma unroll
            for (int j = 0; j < RN; j++)
                acc[i][j] = __builtin_amdgcn_mfma_f32_16x16x32_bf16(af[i], bfr[j], acc[i][j], 0, 0, 0);
        __syncthreads();
    }

    const int n_base = nt * BN + wn * (BN / 2);
    const int m_base = mt * BM + wm * (BM / 2);
    int nj[RN]; float bvj[RN];
    #pragma unroll
    for (int j = 0; j < RN; j++) {
        nj[j] = n_base + j * 16 + lm;
        bvj[j] = 0.f;
        if (nj[j] < N && OUT != 4) {
            if (OUT == 0) bvj[j] = bias[nj[j]];
            else if (OUT == 6) bvj[j] = bias[(nj[j] & 1023) * 9 + (nj[j] >> 10)];
            else if (z == 0) bvj[j] = bias[nj[j]];
        }
    }
    if constexpr (OUT == 4) {
        float* op = (float*)outv;
        #pragma unroll
        for (int i = 0; i < RM; i++)
            #pragma unroll
            for (int r = 0; r < 4; r++) {
                int m = m_base + i * 16 + quad * 4 + r;
                if (m >= M) continue;
                #pragma unroll
                for (int j = 0; j < RN; j++)
                    if (nj[j] < N) atomicAdd(&op[(size_t)m * N + nj[j]], acc[i][j][r]);
            }
    } else if constexpr (OUT == 6) {
        u16* op = (u16*)outv;
        #pragma unroll
        for (int i = 0; i < RM; i++)
            #pragma unroll
            for (int r = 0; r < 4; r++) {
                int m = m_base + i * 16 + quad * 4 + r;
                if (m >= M) continue;
                #pragma unroll
                for (int j = 0; j < RN; j++)
                    if (nj[j] < N) op[(size_t)m * N + nj[j]] = f2bf(acc[i][j][r] + bvj[j]);
            }
    } else if constexpr (OUT == 0) {
        int ohw = OH * OW;
        float sj[RN], qj[RN];
        #pragma unroll
        for (int j = 0; j < RN; j++) { sj[j] = 0.f; qj[j] = 0.f; }
        #pragma unroll
        for (int i = 0; i < RM; i++) {
            int m0 = m_base + i * 16 + quad * 4;
            if (m0 >= M) continue;
            int b = m0 / ohw, pix = m0 - b * ohw;  // ohw%4==0, m0%4==0 -> same image
            #pragma unroll
            for (int j = 0; j < RN; j++) {
                if (nj[j] >= N) continue;
                #pragma unroll
                for (int r = 0; r < 4; r++) {
                    float val = acc[i][j][r] + bvj[j];
                    ((u16*)outv)[((size_t)b * ohw + pix + r) * N + nj[j]] = f2bf(val);
                    if (STATS) {
                        float lv = val >= 0.f ? val : 0.01f * val;
                        sj[j] += lv; qj[j] += lv * lv;
                    }
                }
            }
        }
        if constexpr (STATS) {
            #pragma unroll
            for (int j = 0; j < RN; j++) {
                float s = sj[j], q = qj[j];
                s += __shfl_down(s, 32); q += __shfl_down(q, 32);
                s += __shfl_down(s, 16); q += __shfl_down(q, 16);
                if (quad == 0 && nj[j] < N) {
                    atomicAdd(&stat[nj[j]], s);
                    atomicAdd(&stat[N + nj[j]], q);
                }
            }
        }
    } else {  // OUT 1
        int ohw = OH * OW;
        #pragma unroll
        for (int i = 0; i < RM; i++) {
            int m0 = m_base + i * 16 + quad * 4;
            if (m0 >= M) continue;
            int b = m0 / ohw, pix = m0 - b * ohw;
            #pragma unroll
            for (int j = 0; j < RN; j++) {
                if (nj[j] >= N) continue;
                #pragma unroll
                for (int r = 0; r < 4; r++)
                    atomicAdd(&((float*)outv)[((size_t)b * ohw + pix + r) * N + nj[j]],
                              acc[i][j][r] + bvj[j]);
            }
        }
    }
}

// =========== all-class convT GEMM: grid.z = parity class ===========
template<int BM>
__global__ __launch_bounds__(256, 3)
void gemm_ct(const u16* __restrict__ Abf, const u16* __restrict__ Wb,
             const float* __restrict__ bias, u16* __restrict__ out,
             int N, int lgC, int IH, int IW, int OH, int OW,
             int4 Kc, int4 Mc, int4 Hc, int4 Wc, int4 Oc, int4 Dy, int4 Dx)
{
    constexpr int ANSEG = BM / 64;
    constexpr int RM = BM / 32, RN = 2;
    const int c = blockIdx.z;
    const int Ks[4] = {Kc.x, Kc.y, Kc.z, Kc.w};
    const int Ms[4] = {Mc.x, Mc.y, Mc.z, Mc.w};
    const int Hs[4] = {Hc.x, Hc.y, Hc.z, Hc.w};
    const int Wsz[4]= {Wc.x, Wc.y, Wc.z, Wc.w};
    const int Os[4] = {Oc.x, Oc.y, Oc.z, Oc.w};
    const int Dys[4]= {Dy.x, Dy.y, Dy.z, Dy.w};
    const int Dxs[4]= {Dx.x, Dx.y, Dx.z, Dx.w};
    const int K = Ks[c], M = Ms[c], OHc = Hs[c], OWc = Wsz[c];
    const int dyp = Dys[c], dxp = Dxs[c];
    const int mt = blockIdx.x, nt = blockIdx.y;
    if (mt * BM >= M) return;
    const u16* Bw = Wb + Os[c];

    __shared__ __align__(16) u16 As[4 * BM * 8];
    __shared__ __align__(16) u16 Bs[4 * 64 * 8];
    const int t = threadIdx.x;
    const int lane = t & 63, wave = t >> 6;
    const int lm = lane & 15, quad = lane >> 4;
    const int wm = wave & 1, wn = wave >> 1;

    const int arow = (ANSEG == 2) ? (t >> 1) : (t >> 2);
    const int akb  = (ANSEG == 2) ? (t & 1) * 16 : (t & 3) * 8;
    const int a_gm = mt * BM + arow;
    const bool a_in = a_gm < M;
    const int ohwc = OHc * OWc;
    int g = a_in ? a_gm : 0;
    int bimg = g / ohwc; int rr = g - bimg * ohwc;
    int oy = rr / OWc, ox = rr - (rr / OWc) * OWc;

    const int brow = t >> 2;
    const int bkb  = (t & 3) * 8;
    const int b_gn = nt * 64 + brow;
    const bool b_in = b_gn < N;

    // ---- incremental A state ----
    const int Cmask = (1 << lgC) - 1;
    int ic_s = akb & Cmask;
    int ti_s = 0;
    bool aok; const u16* aptr;
    {
        int sh = 8 * (ti_s & 3);
        int dy = (int)(signed char)((dyp >> sh) & 255);
        int dx = (int)(signed char)((dxp >> sh) & 255);
        int iy = oy + dy, ix = ox + dx;
        aok = a_in && (unsigned)iy < (unsigned)IH && (unsigned)ix < (unsigned)IW;
        aptr = Abf + ((((size_t)bimg * IH + iy) * IW + ix) << lgC);
    }
    const u16* bptr = Bw + (size_t)b_gn * K + bkb;

    auto ldA = [&](uint4 (&v)[ANSEG]) {
        #pragma unroll
        for (int s = 0; s < ANSEG; s++) {
            uint4 x4 = make_uint4(0, 0, 0, 0);
            if (aok) x4 = *(const uint4*)(aptr + ic_s + s * 8);
            v[s] = x4;
        }
        ic_s += 32;
        if (ic_s > Cmask) {            // block-uniform wrap
            ic_s -= Cmask + 1;
            ti_s++;
            int sh = 8 * (ti_s & 3);   // &3 avoids UB shift on final advance
            int dy = (int)(signed char)((dyp >> sh) & 255);
            int dx = (int)(signed char)((dxp >> sh) & 255);
            int iy = oy + dy, ix = ox + dx;
            aok = a_in && (unsigned)iy < (unsigned)IH && (unsigned)ix < (unsigned)IW;
            aptr = Abf + ((((size_t)bimg * IH + iy) * IW + ix) << lgC);
        }
    };
    auto ldB = [&](uint4& v) {
        uint4 x4 = make_uint4(0, 0, 0, 0);
        if (b_in) x4 = *(const uint4*)bptr;
        v = x4;
        bptr += 32;
    };

    f32x4 acc[RM][RN];
    #pragma unroll
    for (int i = 0; i < RM; i++)
        #pragma unroll
        for (int j = 0; j < RN; j++) acc[i][j] = (f32x4){0.f, 0.f, 0.f, 0.f};

    uint4 va[ANSEG]; uint4 vb;
    ldA(va); ldB(vb);
    for (int kb = 0; kb < K; kb += 32) {
        #pragma unroll
        for (int s = 0; s < ANSEG; s++)
            *(uint4*)&As[(((akb >> 3) + s) * BM + arow) * 8] = va[s];
        *(uint4*)&Bs[((bkb >> 3) * 64 + brow) * 8] = vb;
        __syncthreads();
        if (kb + 32 < K) { ldA(va); ldB(vb); }
        bf16x8 af[RM], bfr[RN];
        #pragma unroll
        for (int i = 0; i < RM; i++)
            af[i] = *(const bf16x8*)&As[(size_t)(quad * BM + wm * (BM / 2) + i * 16 + lm) * 8];
        #pragma unroll
        for (int j = 0; j < RN; j++)
            bfr[j] = *(const bf16x8*)&Bs[(size_t)(quad * 64 + wn * 32 + j * 16 + lm) * 8];
        #pragma unroll
        for (int i = 0; i < RM; i++)
            #pragma unroll
            for (int j = 0; j < RN; j++)
                acc[i][j] = __builtin_amdgcn_mfma_f32_16x16x32_bf16(af[i], bfr[j], acc[i][j], 0, 0, 0);
        __syncthreads();
    }

    const int n_base = nt * 64 + wn * 32;
    const int m_base = mt * BM + wm * (BM / 2);
    const int cy = c >> 1, cx = c & 1;
    const int OHW = OH * OW;
    int nj[RN]; float bvj[RN];
    #pragma unroll
    for (int j = 0; j < RN; j++) {
        nj[j] = n_base + j * 16 + lm;
        bvj[j] = (nj[j] < N) ? bias[nj[j]] : 0.f;
    }
    #pragma unroll
    for (int i = 0; i < RM; i++)
        #pragma unroll
        for (int r = 0; r < 4; r++) {
            int m = m_base + i * 16 + quad * 4 + r;
            if (m >= M) continue;
            int b = m / ohwc, r2 = m - b * ohwc;
            int oyc = r2 / OWc, oxc = r2 - (r2 / OWc) * OWc;
            size_t ad0 = ((size_t)b * OHW + (2 * oyc + cy) * OW + 2 * oxc + cx) * N;
            #pragma unroll
            for (int j = 0; j < RN; j++)
                if (nj[j] < N) out[ad0 + nj[j]] = f2bf(acc[i][j][r] + bvj[j]);
        }
}

// ===================== weight prep =====================
// per-oc LDS transpose: src [OC][CIN][9] f32 (coalesced read) ->
// dst [OC][tap][CIN] bf16 (coalesced write)
__global__ __launch_bounds__(256)
void convw_prep(const float* __restrict__ src, u16* __restrict__ dst, int lgC) {
    __shared__ float tl[9216];
    int CIN = 1 << lgC;
    int n = CIN * 9;
    size_t base = (size_t)blockIdx.x * n;
    for (int i = threadIdx.x; i < n; i += 256) tl[i] = src[base + i];
    __syncthreads();
    for (int j = threadIdx.x; j < n; j += 256) {
        int tap = j >> lgC, ic = j & (CIN - 1);
        dst[base + j] = f2bf(tl[ic * 9 + tap]);
    }
}

// dec weight: transpose [800][9216] f32 -> rows n' = (n%9)*1024 + n/9 of
// W_dec[n'][800] bf16, so the dec GEMM's output columns are already in the
// d0 NHWC order (coalesced OUT=6 writes).
__global__ __launch_bounds__(256)
void transpose_cvt_dec(const float* __restrict__ in, u16* __restrict__ out) {
    __shared__ float tl[32][33];
    int c0 = blockIdx.x * 32, r0 = blockIdx.y * 32;
    int tx = threadIdx.x & 31, ty = threadIdx.x >> 5;
    #pragma unroll
    for (int l = 0; l < 4; l++)
        tl[ty + 8 * l][tx] = in[(size_t)(r0 + ty + 8 * l) * 9216 + c0 + tx];
    __syncthreads();
    #pragma unroll
    for (int l = 0; l < 4; l++) {
        int n = c0 + ty + 8 * l;
        int cc = n / 9, hw = n - 9 * cc;
        out[(size_t)(hw * 1024 + cc) * 800 + r0 + tx] = f2bf(tl[tx][ty + 8 * l]);
    }
}

// fused transpose + parity-class gather for convT weights:
// in  = [CIN][OC*9] f32 (ic-major, as given)
// out = per class cls: off[cls] + oc*K[cls] + ti*CIN + ic  (bf16)
__global__ __launch_bounds__(256)
void ctw_fused(const float* __restrict__ in, u16* __restrict__ outw,
               int CIN, int P, int4 Kc, int4 Oc) {
    __shared__ float tl[32][33];
    int c0 = blockIdx.x * 32, r0 = blockIdx.y * 32;
    int C = gridDim.x * 32;                       // = OC*9
    int tx = threadIdx.x & 31, ty = threadIdx.x >> 5;
    #pragma unroll
    for (int l = 0; l < 4; l++)
        tl[ty + 8 * l][tx] = in[(size_t)(r0 + ty + 8 * l) * C + c0 + tx];
    __syncthreads();
    const int Ks[4] = {Kc.x, Kc.y, Kc.z, Kc.w};
    const int Os[4] = {Oc.x, Oc.y, Oc.z, Oc.w};
    int ic = r0 + tx;
    #pragma unroll
    for (int l = 0; l < 4; l++) {
        int cc = c0 + ty + 8 * l;
        int oc = cc / 9, tap = cc - 9 * oc;
        int ky = tap / 3, kx = tap - 3 * (tap / 3);
        int cyc = (P + ky) & 1, cxc = (P + kx) & 1;
        int cls = cyc * 2 + cxc;
        int nkx = ((P ^ cxc) & 1) ? 1 : 2;
        int ti = (ky >> 1) * nkx + (kx >> 1);
        outw[Os[cls] + (size_t)oc * Ks[cls] + ti * CIN + ic] = f2bf(tl[tx][ty + 8 * l]);
    }
}

__global__ __launch_bounds__(256)
void fcw_prep(const float* __restrict__ in, u16* __restrict__ out) {
    __shared__ float tl[32][33];
    int n0 = blockIdx.x * 32, c0 = blockIdx.y * 32, hw = blockIdx.z;
    int tx = threadIdx.x & 31, ty = threadIdx.x >> 5;
    #pragma unroll
    for (int l = 0; l < 4; l++)
        tl[ty + 8 * l][tx] = in[((size_t)(c0 + ty + 8 * l) * 16 + hw) * 800 + n0 + tx];
    __syncthreads();
    #pragma unroll
    for (int l = 0; l < 4; l++)
        out[(size_t)(n0 + ty + 8 * l) * 16384 + hw * 1024 + c0 + tx] = f2bf(tl[tx][ty + 8 * l]);
}

__global__ __launch_bounds__(256)
void wt5_prep(const float* __restrict__ in, u16* __restrict__ out) {
    int idx = blockIdx.x * 256 + threadIdx.x;
    if (idx >= 576) return;
    int tap = idx >> 6, ic = idx & 63;
    out[idx] = f2bf(in[ic * 9 + tap]);
}

// ===================== non-GEMM =====================
// conv1 with fused BN stats: grid-stride (stride 262144 = 0 mod 128 so each
// thread has a fixed oc -> weights in registers, per-thread s/q accumulate).
__global__ __launch_bounds__(256)
void conv1_stat(const float* __restrict__ x, const float* __restrict__ w,
                const float* __restrict__ bias, u16* __restrict__ out,
                float* __restrict__ accum) {
    __shared__ float ls[256];
    ls[threadIdx.x] = 0.f;
    __syncthreads();
    int idx0 = blockIdx.x * 256 + threadIdx.x;
    int oc = idx0 & 127;
    float wreg[9];
    const float* wp = w + oc * 9;
    #pragma unroll
    for (int k = 0; k < 9; k++) wreg[k] = wp[k];
    float bz = bias[oc];
    float s = 0.f, q = 0.f;
    for (int idx = idx0; idx < 13107200; idx += 262144) {
        int pix = (idx >> 7) & 1023;
        int b = idx >> 17;
        int oy = pix >> 5, ox = pix & 31;
        int iy0 = oy * 2 - 1, ix0 = ox * 2 - 1;
        float acc = bz;
        const float* ip = x + (size_t)b * 4096;
        #pragma unroll
        for (int ky = 0; ky < 3; ky++) {
            int iy = iy0 + ky;
            if ((unsigned)iy >= 64u) continue;
            #pragma unroll
            for (int kx = 0; kx < 3; kx++) {
                int ix = ix0 + kx;
                if ((unsigned)ix >= 64u) continue;
                acc = fmaf(ip[iy * 64 + ix], wreg[ky * 3 + kx], acc);
            }
        }
        out[idx] = f2bf(acc);
        float lv = acc >= 0.f ? acc : 0.01f * acc;
        s += lv; q += lv * lv;
    }
    atomicAdd(&ls[oc], s);
    atomicAdd(&ls[128 + oc], q);
    __syncthreads();
    atomicAdd(&accum[threadIdx.x], ls[threadIdx.x]);
}

// vectorized bf16x8 BN apply (leaky + normalize), in-place safe
__global__ __launch_bounds__(256)
void bnapply8(const u16* __restrict__ x, u16* __restrict__ out,
              const float* __restrict__ accum, int C, int total, float invcnt) {
    int i8 = (blockIdx.x * 256 + threadIdx.x) * 8;
    if (i8 >= total) return;
    int c0 = i8 & (C - 1);
    uint4 v = *(const uint4*)(x + i8);
    const unsigned* w = (const unsigned*)&v;
    uint4 o;
    unsigned* ow = (unsigned*)&o;
    #pragma unroll
    for (int h = 0; h < 4; h++) {
        float m0 = accum[c0 + 2 * h] * invcnt, m1 = accum[c0 + 2 * h + 1] * invcnt;
        float q0 = accum[C + c0 + 2 * h] * invcnt, q1 = accum[C + c0 + 2 * h + 1] * invcnt;
        float in0 = rsqrtf(q0 - m0 * m0 + 1e-5f);
        float in1 = rsqrtf(q1 - m1 * m1 + 1e-5f);
        float v0 = __builtin_bit_cast(float, w[h] << 16);
        float v1 = __builtin_bit_cast(float, w[h] & 0xFFFF0000u);
        v0 = v0 >= 0.f ? v0 : 0.01f * v0;
        v1 = v1 >= 0.f ? v1 : 0.01f * v1;
        unsigned r0 = f2bf((v0 - m0) * in0);
        unsigned r1 = f2bf((v1 - m1) * in1);
        ow[h] = r0 | (r1 << 16);
    }
    *(uint4*)(out + i8) = o;
}

// f32 x4 variants (conv4 split-K accumulator path)
__global__ __launch_bounds__(256)
void bnstat4f(const float* __restrict__ x, float* __restrict__ accum, int C, int total) {
    __shared__ float ls[2048];
    for (int i = threadIdx.x; i < 2 * C; i += 256) ls[i] = 0.f;
    __syncthreads();
    int base = (blockIdx.x * 256 + threadIdx.x) * 4;
    int stride = gridDim.x * 1024;
    float s[4] = {0, 0, 0, 0}, q[4] = {0, 0, 0, 0};
    for (int i = base; i < total; i += stride) {
        f32x4 v = *(const f32x4*)(x + i);
        #pragma unroll
        for (int r = 0; r < 4; r++) {
            float vv = v[r]; vv = vv >= 0.f ? vv : 0.01f * vv;
            s[r] += vv; q[r] += vv * vv;
        }
    }
    int c0 = base & (C - 1);
    #pragma unroll
    for (int r = 0; r < 4; r++) {
        atomicAdd(&ls[c0 + r], s[r]);
        atomicAdd(&ls[C + c0 + r], q[r]);
    }
    __syncthreads();
    for (int i = threadIdx.x; i < 2 * C; i += 256) atomicAdd(&accum[i], ls[i]);
}

__global__ __launch_bounds__(256)
void bnapply4f(const float* __restrict__ x, u16* __restrict__ out,
               const float* __restrict__ accum, int C, int total, float invcnt) {
    int i4 = (blockIdx.x * 256 + threadIdx.x) * 4;
    if (i4 >= total) return;
    int c0 = i4 & (C - 1);
    f32x4 v = *(const f32x4*)(x + i4);
    unsigned r4[4];
    #pragma unroll
    for (int r = 0; r < 4; r++) {
        float m = accum[c0 + r] * invcnt;
        float var = accum[C + c0 + r] * invcnt - m * m;
        float inv = rsqrtf(var + 1e-5f);
        float vv = v[r]; vv = vv >= 0.f ? vv : 0.01f * vv;
        r4[r] = f2bf((vv - m) * inv);
    }
    *(uint2*)(out + i4) = make_uint2(r4[0] | (r4[1] << 16), r4[2] | (r4[3] << 16));
}

// fused: relu(facc+bias) -> eig (output) + DFT rows
__global__ __launch_bounds__(256)
void dft_real(const float* __restrict__ facc, const float* __restrict__ fcb,
              float* __restrict__ eig, float* __restrict__ Yr, u16* __restrict__ Yrb) {
    __shared__ float se[800];
    __shared__ float ctab[800];
    int b = blockIdx.x;
    for (int i = threadIdx.x; i < 800; i += 256) {
        float v = fmaxf(facc[b * 800 + i] + fcb[i], 0.f);
        se[i] = v;
        if (blockIdx.y == 0) eig[b * 800 + i] = v;
        ctab[i] = cospif(i * 0.0025f);   // cos(2*pi*i/800)
    }
    __syncthreads();
    int o0 = blockIdx.y * 400;
    for (int oi = o0 + threadIdx.x; oi < o0 + 400; oi += 256) {
        int k1 = oi >> 3, k2 = oi & 7;
        int d1 = k1 * 8, d2 = k2 * 100;
        float acc0 = 0.f, acc1 = 0.f;
        int p1 = 0;
        for (int n1 = 0; n1 < 100; n1 += 2) {
            int p = p1;
            #pragma unroll
            for (int n2 = 0; n2 < 8; n2++) {
                acc0 = fmaf(se[n1 * 8 + n2], ctab[p], acc0);
                p += d2; if (p >= 800) p -= 800;
            }
            int pb = p1 + d1; if (pb >= 800) pb -= 800;
            int p2 = pb;
            #pragma unroll
            for (int n2 = 0; n2 < 8; n2++) {
                acc1 = fmaf(se[(n1 + 1) * 8 + n2], ctab[p2], acc1);
                p2 += d2; if (p2 >= 800) p2 -= 800;
            }
            p1 = pb + d1; if (p1 >= 800) p1 -= 800;
        }
        float acc = acc0 + acc1;
        Yr[b * 800 + oi] = acc;
        Yrb[b * 800 + oi] = f2bf(acc);
    }
}

__global__ __launch_bounds__(256)
void build_C4(const float* __restrict__ Yr, float* __restrict__ C) {
    int idx = blockIdx.x * 256 + threadIdx.x;
    if (idx >= 100 * 800 * 200) return;
    int j4 = (idx % 200) * 4; int tt = idx / 200;
    int i = tt % 800;         int b = tt / 800;
    const float* y = Yr + b * 800;
    f32x4 v;
    #pragma unroll
    for (int r = 0; r < 4; r++) {
        int k = i - (j4 + r);
        k += (k >> 31) & 800;
        v[r] = y[k] * 0.035355339059327376f;
    }
    ((f32x4*)C)[idx] = v;
}

__global__ __launch_bounds__(256)
void convT5(const u16* __restrict__ in, const u16* __restrict__ w,
            const float* __restrict__ bias, float* __restrict__ out) {
    int idx = blockIdx.x * 256 + threadIdx.x;
    if (idx >= 100 * 49 * 49) return;
    int ox = idx % 49; int t2 = idx / 49;
    int oy = t2 % 49;  int b = t2 / 49;
    float ac[8];
    #pragma unroll
    for (int r = 0; r < 8; r++) ac[r] = 0.f;
    for (int ky = 0; ky < 3; ky++) {
        int iy = oy - ky;
        if ((unsigned)iy >= 47u) continue;
        for (int kx = 0; kx < 3; kx++) {
            int ix = ox - kx;
            if ((unsigned)ix >= 47u) continue;
            const uint4* ip = (const uint4*)(in + (((size_t)b * 47 + iy) * 47 + ix) * 64);
            const uint4* wp = (const uint4*)(w + (ky * 3 + kx) * 64);
            #pragma unroll
            for (int g = 0; g < 8; g++) {
                uint4 av = ip[g], wv = wp[g];
                const unsigned* aa = (const unsigned*)&av;
                const unsigned* ww = (const unsigned*)&wv;
                #pragma unroll
                for (int h = 0; h < 4; h++) {
                    float a0 = __builtin_bit_cast(float, aa[h] << 16);
                    float a1 = __builtin_bit_cast(float, aa[h] & 0xFFFF0000u);
                    float w0 = __builtin_bit_cast(float, ww[h] << 16);
                    float w1 = __builtin_bit_cast(float, ww[h] & 0xFFFF0000u);
                    int rix = ((g & 1) << 2) | h;   // 8 independent chains
                    ac[rix] = fmaf(a0, w0, ac[rix]);
                    ac[rix] = fmaf(a1, w1, ac[rix]);
                }
            }
        }
    }
    out[idx] = bias[0] + ((ac[0] + ac[1]) + (ac[2] + ac[3]))
                       + ((ac[4] + ac[5]) + (ac[6] + ac[7]));
}

// ===================== host helpers =====================
struct CTClass { int T, OHc, OWc, dyp, dxp, off, K; };
static void ct_params(int P, int OH, int OW, int CIN, int OC, CTClass cls[4]) {
    int off = 0;
    for (int c = 0; c < 4; c++) {
        int cy = c >> 1, cx = c & 1;
        int kys[2], dys[2], nky = 0, kxs[2], dxs[2], nkx = 0;
        for (int ky = 0; ky < 3; ky++)
            if (((cy + P + ky) & 1) == 0) { kys[nky] = ky; dys[nky] = (cy + P - ky) / 2; nky++; }
        for (int kx = 0; kx < 3; kx++)
            if (((cx + P + kx) & 1) == 0) { kxs[nkx] = kx; dxs[nkx] = (cx + P - kx) / 2; nkx++; }
        CTClass& cc = cls[c];
        cc.T = nky * nkx;
        cc.OHc = (OH - cy + 1) >> 1; cc.OWc = (OW - cx + 1) >> 1;
        cc.dyp = 0; cc.dxp = 0;
        int ti = 0;
        for (int a = 0; a < nky; a++)
            for (int b2 = 0; b2 < nkx; b2++, ti++) {
                cc.dyp |= (dys[a] & 255) << (8 * ti);
                cc.dxp |= (dxs[b2] & 255) << (8 * ti);
            }
        cc.off = off; cc.K = CIN * cc.T;
        off += OC * cc.K;
    }
}

template<int BM>
static void launch_ct(hipStream_t s, const u16* in, const u16* W, const float* bias, u16* outp,
                      int lgC, int OC, int IH, int IW, int OH, int OW, const CTClass* cls) {
    int maxMT = 0;
    for (int c = 0; c < 4; c++) {
        int mt = (100 * cls[c].OHc * cls[c].OWc + BM - 1) / BM;
        if (mt > maxMT) maxMT = mt;
    }
    dim3 g(maxMT, (OC + 63) / 64, 4);
    gemm_ct<BM><<<g, 256, 0, s>>>(in, W, bias, outp, OC, lgC, IH, IW, OH, OW,
        make_int4(cls[0].K, cls[1].K, cls[2].K, cls[3].K),
        make_int4(100*cls[0].OHc*cls[0].OWc, 100*cls[1].OHc*cls[1].OWc,
                  100*cls[2].OHc*cls[2].OWc, 100*cls[3].OHc*cls[3].OWc),
        make_int4(cls[0].OHc, cls[1].OHc, cls[2].OHc, cls[3].OHc),
        make_int4(cls[0].OWc, cls[1].OWc, cls[2].OWc, cls[3].OWc),
        make_int4(cls[0].off, cls[1].off, cls[2].off, cls[3].off),
        make_int4(cls[0].dyp, cls[1].dyp, cls[2].dyp, cls[3].dyp),
        make_int4(cls[0].dxp, cls[1].dxp, cls[2].dxp, cls[3].dxp));
}

static void launch_ctw(hipStream_t s, const float* w, u16* outw,
                       int CIN, int OC, int P, const CTClass* cls) {
    dim3 g((OC * 9) / 32, CIN / 32);
    ctw_fused<<<g, 256, 0, s>>>(w, outw, CIN, P,
        make_int4(cls[0].K, cls[1].K, cls[2].K, cls[3].K),
        make_int4(cls[0].off, cls[1].off, cls[2].off, cls[3].off));
}

extern "C" void kernel_launch(void* const* d_in, const int* in_sizes, int n_in,
                              void* d_out, int out_size, void* d_ws, size_t ws_size,
                              hipStream_t stream) {
    const float* x    = (const float*)d_in[0];
    const float* c1w  = (const float*)d_in[1];  const float* c1b = (const float*)d_in[2];
    const float* c2w  = (const float*)d_in[3];  const float* c2b = (const float*)d_in[4];
    const float* c3w  = (const float*)d_in[5];  const float* c3b = (const float*)d_in[6];
    const float* c4w  = (const float*)d_in[7];  const float* c4b = (const float*)d_in[8];
    const float* fcw  = (const float*)d_in[9];  const float* fcb = (const float*)d_in[10];
    const float* decw = (const float*)d_in[11]; const float* decb = (const float*)d_in[12];
    const float* t1w  = (const float*)d_in[13]; const float* t1b = (const float*)d_in[14];
    const float* t2w  = (const float*)d_in[15]; const float* t2b = (const float*)d_in[16];
    const float* t3w  = (const float*)d_in[17]; const float* t3b = (const float*)d_in[18];
    const float* t4w  = (const float*)d_in[19]; const float* t4b = (const float*)d_in[20];
    const float* t5w  = (const float*)d_in[21]; const float* t5b = (const float*)d_in[22];

    float* out = (float*)d_out;
    float* d_final = out;
    float* Cmat    = out + 240100;
    float* eig     = out + 240100 + 64000000;

    float* ws = (float*)d_ws;
    // ---- encoder-phase workspace (float units) ----
    u16*   h1    = (u16*)(ws);                 // 13,107,200 bf16
    u16*   W_fc  = (u16*)(ws);                 // reuse @0 after conv2
    u16*   h2    = (u16*)(ws + 6553600);
    u16*   h3    = (u16*)(ws + 9830400);
    u16*   W_c2  = (u16*)(ws + 13107200);
    u16*   W_c3  = (u16*)(ws + 13254656);
    u16*   W_c4  = (u16*)(ws + 14434304);
    float* h4f   = ws + 19152896;              // 1,638,400 f32
    u16*   h4    = (u16*)(ws + 20791296);
    float* accs  = ws + 21610496;              // 8,192 f32 (4 layer slices)
    float* facc  = ws + 21618688;              // 80,000 f32
    float* Yr    = ws + 21698688;              // 80,000 f32
    u16*   Yrb   = (u16*)(ws + 21778688);      // 80,000 bf16
    u16*   d0    = (u16*)(ws + 21818688);      // 921,600 bf16
    u16*   W_dec = (u16*)(ws + 22279488);      // 7,372,800 bf16 -> ends 25,965,888
    float* acc1 = accs, *acc2 = accs + 2048, *acc3 = accs + 4096, *acc4 = accs + 6144;
    // ---- decoder-phase (encoder region dead) ----
    u16*   W_t   = (u16*)(ws);                 // up to 4,718,592 bf16
    u16*   o1    = (u16*)(ws + 4718592);       // 1,280,000 bf16
    u16*   o2    = (u16*)(ws + 5358592);       // 3,097,600 bf16
    u16*   o3    = (u16*)(ws + 6907392);       // 6,771,200 bf16
    u16*   o4    = (u16*)(ws + 10292992);      // 14,137,600 bf16
    u16*   W_t5  = (u16*)(ws + 17361792);

    #define GRID(n) dim3(((n) + 255) / 256)

    // clear all BN-stat slices + facc in one fill
    hipMemsetAsync(accs, 0, (8192 + 80000) * 4, stream);

    // ======== encoder ========
    conv1_stat<<<dim3(1024), 256, 0, stream>>>(x, c1w, c1b, h1, acc1);
    bnapply8<<<GRID(1638400), 256, 0, stream>>>(h1, h1, acc1, 128, 13107200, 1.f / 102400.f);

    convw_prep<<<dim3(256), 256, 0, stream>>>(c2w, W_c2, 7);
    gemm<1, 0, 128, 128, 0, true, true><<<dim3(200, 2, 1), 256, 0, stream>>>(
        h1, W_c2, c2b, h2, acc2, 25600, 256, 1152, 7, 32, 32, 16, 16, 1152);
    bnapply8<<<GRID(819200), 256, 0, stream>>>(h2, h2, acc2, 256, 6553600, 1.f / 25600.f);

    convw_prep<<<dim3(1024), 256, 0, stream>>>(c3w, W_c3, 8);
    gemm<1, 0, 128, 128, 1, true, true><<<dim3(400, 1, 1), 256, 0, stream>>>(
        h2, W_c3, c3b, h3, acc3, 6400, 1024, 2304, 8, 16, 16, 8, 8, 2304);
    bnapply8<<<GRID(819200), 256, 0, stream>>>(h3, h3, acc3, 1024, 6553600, 1.f / 6400.f);

    convw_prep<<<dim3(1024), 256, 0, stream>>>(c4w, W_c4, 10);
    hipMemsetAsync(h4f, 0, 1638400 * 4, stream);
    gemm<1, 1, 64, 128, 1, false, true><<<dim3(400, 1, 1), 256, 0, stream>>>(
        h3, W_c4, c4b, h4f, nullptr, 1600, 1024, 9216, 10, 8, 8, 4, 4, 4608);
    bnstat4f<<<1024, 256, 0, stream>>>(h4f, acc4, 1024, 1638400);
    bnapply4f<<<GRID(409600), 256, 0, stream>>>(h4f, h4, acc4, 1024, 1638400, 1.f / 1600.f);

    // ======== fc (split-K z=16) ========
    fcw_prep<<<dim3(25, 32, 16), 256, 0, stream>>>(fcw, W_fc);
    gemm<0, 4, 64, 64, 0, false, true><<<dim3(2, 13, 16), 256, 0, stream>>>(
        h4, W_fc, nullptr, facc, nullptr, 100, 800, 16384, 0, 0, 0, 0, 0, 1024);

    // ======== FFT block (relu fused into dft) ========
    dft_real<<<dim3(100, 2), 256, 0, stream>>>(facc, fcb, eig, Yr, Yrb);
    build_C4<<<GRID(16000000), 256, 0, stream>>>(Yr, Cmat);

    // ======== dec matmul (permuted weight rows -> coalesced d0 writes) ====
    transpose_cvt_dec<<<dim3(288, 25), 256, 0, stream>>>(decw, W_dec);
    gemm<0, 6, 64, 64, 0, false, true><<<dim3(2, 144, 1), 256, 0, stream>>>(
        Yrb, W_dec, decb, d0, nullptr, 100, 9216, 800, 0, 0, 0, 0, 0, 800);

    // ======== decoder convT stack ========
    CTClass c1c[4], c2c[4], c3c[4], c4c[4];
    ct_params(1, 5, 5, 1024, 512, c1c);
    ct_params(0, 11, 11, 512, 256, c2c);
    ct_params(0, 23, 23, 256, 128, c3c);
    ct_params(0, 47, 47, 128, 64, c4c);

    launch_ctw(stream, t1w, W_t, 1024, 512, 1, c1c);
    launch_ct<64>(stream, d0, W_t, t1b, o1, 10, 512, 3, 3, 5, 5, c1c);

    launch_ctw(stream, t2w, W_t, 512, 256, 0, c2c);
    launch_ct<64>(stream, o1, W_t, t2b, o2, 9, 256, 5, 5, 11, 11, c2c);

    launch_ctw(stream, t3w, W_t, 256, 128, 0, c3c);
    launch_ct<64>(stream, o2, W_t, t3b, o3, 8, 128, 11, 11, 23, 23, c3c);

    launch_ctw(stream, t4w, W_t, 128, 64, 0, c4c);
    launch_ct<128>(stream, o3, W_t, t4b, o4, 7, 64, 23, 23, 47, 47, c4c);

    wt5_prep<<<GRID(576), 256, 0, stream>>>(t5w, W_t5);
    convT5<<<GRID(240100), 256, 0, stream>>>(o4, W_t5, t5b, d_final);

    #undef GRID
}